// Round 4
// baseline (1164.723 us; speedup 1.0000x reference)
//
#include <hip/hip_runtime.h>
#include <hip/hip_bf16.h>

#define NN 100000
#define NE 50000
#define NT 2000
#define DD 128
#define NEDGE 1600000
#define HID 512
#define OUTD 128
#define K1 (3*DD)   // 384
#define NBKT 391              // ceil(100000/256) buckets of 256 nodes

typedef __bf16 bf16x8 __attribute__((ext_vector_type(8)));
typedef __bf16 bf16x4 __attribute__((ext_vector_type(4)));
typedef float  f32x4  __attribute__((ext_vector_type(4)));

__device__ __forceinline__ __bf16 f2b(float f) {
    __hip_bfloat16 h = __float2bfloat16(f);
    union { __hip_bfloat16 h; __bf16 b; } u; u.h = h; return u.b;
}

__device__ __forceinline__ void gll16(const void* g, void* l) {
    __builtin_amdgcn_global_load_lds((const __attribute__((address_space(1))) void*)g,
                                     (__attribute__((address_space(3))) void*)l, 16, 0, 0);
}

__device__ __forceinline__ float ftanh(float x) {
    x = fminf(fmaxf(x, -15.f), 15.f);
    float t = __expf(2.f * x);
    return (t - 1.f) / (t + 1.f);
}

// ---- convert feature tables to bf16 ----
__global__ void conv_feats(const float* __restrict__ entf, const float* __restrict__ topf,
                           __bf16* __restrict__ entb, __bf16* __restrict__ topb) {
    long i = ((long)blockIdx.x * 256 + threadIdx.x) * 4;
    const long NEL = (long)NE * DD;   // 6.4M
    if (i < NEL) {
        float4 v = *(const float4*)(entf + i);
        *(bf16x4*)(entb + i) = bf16x4{f2b(v.x), f2b(v.y), f2b(v.z), f2b(v.w)};
    } else {
        long j = i - NEL;
        float4 v = *(const float4*)(topf + j);
        *(bf16x4*)(topb + j) = bf16x4{f2b(v.x), f2b(v.y), f2b(v.z), f2b(v.w)};
    }
}

// ---- bucket histogram: LDS-local then one global atomic per (block,bucket) ----
__global__ __launch_bounds__(256) void hist_buckets(const int* __restrict__ er,
                                                    const int* __restrict__ tr,
                                                    int* __restrict__ bc_e,
                                                    int* __restrict__ bc_t) {
    __shared__ int lhe[NBKT], lht[NBKT];
    const int tid = threadIdx.x;
    for (int i = tid; i < NBKT; i += 256) { lhe[i] = 0; lht[i] = 0; }
    __syncthreads();
    const int base = blockIdx.x * 8192;
    #pragma unroll 4
    for (int k = 0; k < 32; k++) {
        int e = base + k * 256 + tid;
        if (e < NEDGE) {
            atomicAdd(&lhe[er[e] >> 8], 1);
            atomicAdd(&lht[tr[e] >> 8], 1);
        }
    }
    __syncthreads();
    for (int i = tid; i < NBKT; i += 256) {
        if (lhe[i]) atomicAdd(&bc_e[i], lhe[i]);
        if (lht[i]) atomicAdd(&bc_t[i], lht[i]);
    }
}

// ---- scan 391 bucket counts -> inclusive bc, exclusive cursors; offs[0]=0 ----
__global__ void scan_buckets(int* __restrict__ bc_e, int* __restrict__ bc_t,
                             int* __restrict__ cur_e, int* __restrict__ cur_t,
                             int* __restrict__ offs_e, int* __restrict__ offs_t) {
    int* bc  = blockIdx.y ? bc_t : bc_e;
    int* cur = blockIdx.y ? cur_t : cur_e;
    int* offs = blockIdx.y ? offs_t : offs_e;
    __shared__ int s[512];
    int i = threadIdx.x;
    s[i] = (i < NBKT) ? bc[i] : 0;
    __syncthreads();
    #pragma unroll
    for (int off = 1; off < 512; off <<= 1) {
        int v = (i >= off) ? s[i - off] : 0;
        __syncthreads();
        s[i] += v;
        __syncthreads();
    }
    if (i < NBKT) {
        bc[i] = s[i];
        cur[i] = i ? s[i - 1] : 0;
    }
    if (i == 0) offs[0] = 0;
}

// ---- partition edges into buckets (dense frontier: 391 cursors) ----
__global__ __launch_bounds__(256) void scatter_bucket(const int* __restrict__ er,
                                                      const int* __restrict__ ec,
                                                      const int* __restrict__ tr,
                                                      const int* __restrict__ tc,
                                                      int* __restrict__ cur_e,
                                                      int* __restrict__ cur_t,
                                                      int* __restrict__ be,
                                                      int* __restrict__ bt) {
    const int base = blockIdx.x * 2048;
    #pragma unroll
    for (int k = 0; k < 8; k++) {
        int e = base + k * 256 + threadIdx.x;
        if (e >= NEDGE) continue;
        int r = er[e];
        int p = atomicAdd(&cur_e[r >> 8], 1);
        be[p] = ((r & 255) << 16) | ec[e];
        int r2 = tr[e];
        int q = atomicAdd(&cur_t[r2 >> 8], 1);
        bt[q] = ((r2 & 255) << 16) | tc[e];
    }
}

// ---- per-bucket exact CSR: local hist + scan -> offs + reorder cols ----
__global__ __launch_bounds__(256) void bucket_csr(const int* __restrict__ be,
                                                  const int* __restrict__ bt,
                                                  const int* __restrict__ bc_e,
                                                  const int* __restrict__ bc_t,
                                                  int* __restrict__ offs_e,
                                                  int* __restrict__ offs_t,
                                                  int* __restrict__ se,
                                                  int* __restrict__ st) {
    const int* buf = blockIdx.y ? bt : be;
    const int* bc  = blockIdx.y ? bc_t : bc_e;
    int* offs      = blockIdx.y ? offs_t : offs_e;
    int* sout      = blockIdx.y ? st : se;
    const int b = blockIdx.x;
    const int tid = threadIdx.x;
    const int start = b ? bc[b - 1] : 0;
    const int cnt = bc[b] - start;

    __shared__ int scn[256];
    __shared__ int lcur[256];
    scn[tid] = 0;
    __syncthreads();
    for (int i = tid; i < cnt; i += 256)
        atomicAdd(&scn[buf[start + i] >> 16], 1);
    __syncthreads();
    #pragma unroll
    for (int off = 1; off < 256; off <<= 1) {
        int v = (tid >= off) ? scn[tid - off] : 0;
        __syncthreads();
        scn[tid] += v;
        __syncthreads();
    }
    const int node = b * 256 + tid;
    if (node < NN) offs[node + 1] = start + scn[tid];
    lcur[tid] = start + (tid ? scn[tid - 1] : 0);
    __syncthreads();
    for (int i = tid; i < cnt; i += 256) {
        int v = buf[start + i];
        int p = atomicAdd(&lcur[v >> 16], 1);
        sout[p] = v & 0xFFFF;
    }
}

// ---- gather-aggregate (bf16 tables) + fused X build ----
__global__ __launch_bounds__(256) void aggregate2(const float* __restrict__ news,
                                                  const __bf16* __restrict__ entb,
                                                  const __bf16* __restrict__ topb,
                                                  const int* __restrict__ offs_e,
                                                  const int* __restrict__ offs_t,
                                                  const int* __restrict__ se,
                                                  const int* __restrict__ st,
                                                  __bf16* __restrict__ X) {
    const int wave = threadIdx.x >> 6, lane = threadIdx.x & 63;
    const int node = blockIdx.x * 4 + wave;
    if (node >= NN) return;
    const int h = lane >> 5;
    const int d = (lane & 31) * 4;

    float e0 = 0.f, e1 = 0.f, e2 = 0.f, e3 = 0.f;
    float p0 = 0.f, p1 = 0.f, p2 = 0.f, p3 = 0.f;

    const int s0 = offs_e[node], s1 = offs_e[node + 1];
    int i = s0 + h;
    for (; i + 2 < s1; i += 4) {
        int c0 = se[i], c1 = se[i + 2];
        bf16x4 v0 = *(const bf16x4*)(entb + (long)c0 * DD + d);
        bf16x4 v1 = *(const bf16x4*)(entb + (long)c1 * DD + d);
        e0 += (float)v0[0] + (float)v1[0];
        e1 += (float)v0[1] + (float)v1[1];
        e2 += (float)v0[2] + (float)v1[2];
        e3 += (float)v0[3] + (float)v1[3];
    }
    if (i < s1) {
        bf16x4 v = *(const bf16x4*)(entb + (long)se[i] * DD + d);
        e0 += (float)v[0]; e1 += (float)v[1]; e2 += (float)v[2]; e3 += (float)v[3];
    }

    const int t0 = offs_t[node], t1 = offs_t[node + 1];
    i = t0 + h;
    for (; i + 2 < t1; i += 4) {
        int c0 = st[i], c1 = st[i + 2];
        bf16x4 v0 = *(const bf16x4*)(topb + (long)c0 * DD + d);
        bf16x4 v1 = *(const bf16x4*)(topb + (long)c1 * DD + d);
        p0 += (float)v0[0] + (float)v1[0];
        p1 += (float)v0[1] + (float)v1[1];
        p2 += (float)v0[2] + (float)v1[2];
        p3 += (float)v0[3] + (float)v1[3];
    }
    if (i < t1) {
        bf16x4 v = *(const bf16x4*)(topb + (long)st[i] * DD + d);
        p0 += (float)v[0]; p1 += (float)v[1]; p2 += (float)v[2]; p3 += (float)v[3];
    }

    e0 += __shfl_xor(e0, 32, 64); e1 += __shfl_xor(e1, 32, 64);
    e2 += __shfl_xor(e2, 32, 64); e3 += __shfl_xor(e3, 32, 64);
    p0 += __shfl_xor(p0, 32, 64); p1 += __shfl_xor(p1, 32, 64);
    p2 += __shfl_xor(p2, 32, 64); p3 += __shfl_xor(p3, 32, 64);

    const float ie = 1.0f / ((float)(s1 - s0) + 1e-8f);
    const float it = 1.0f / ((float)(t1 - t0) + 1e-8f);
    __bf16* xr = X + (long)node * K1;
    if (h == 0) {
        float4 nv = *(const float4*)(news + (long)node * DD + d);
        *(bf16x4*)(xr + d)      = bf16x4{f2b(nv.x), f2b(nv.y), f2b(nv.z), f2b(nv.w)};
        *(bf16x4*)(xr + DD + d) = bf16x4{f2b(e0 * ie), f2b(e1 * ie), f2b(e2 * ie), f2b(e3 * ie)};
    } else {
        *(bf16x4*)(xr + 2*DD + d) = bf16x4{f2b(p0 * it), f2b(p1 * it), f2b(p2 * it), f2b(p3 * it)};
    }
}

// ---- W1 [384,512] -> W1T bf16 [512,384]; W2 [512,128] -> W2T bf16 [128,512] ----
__global__ void conv_w(const float* __restrict__ W1, const float* __restrict__ W2,
                       __bf16* __restrict__ W1T, __bf16* __restrict__ W2T) {
    int i = blockIdx.x * 256 + threadIdx.x;
    if (i < K1 * HID) {
        int k = i / HID, n = i % HID;
        W1T[n * K1 + k] = f2b(W1[i]);
    } else {
        int j = i - K1 * HID;
        if (j < HID * OUTD) {
            int k = j / OUTD, n = j % OUTD;
            W2T[n * HID + k] = f2b(W2[j]);
        }
    }
}

// ---- m97-style 128x128 GEMM: C[M,N] = act(A[M,K] @ BT[N,K]^T + bias) ----
template<int TANH>
__global__ __launch_bounds__(256) void gemm128(const __bf16* __restrict__ A,
                                               const __bf16* __restrict__ BT,
                                               const float* __restrict__ bias,
                                               void* __restrict__ Cout,
                                               int M, int N, int K) {
    __shared__ __bf16 As[128 * 32];
    __shared__ __bf16 Bs[128 * 32];
    const int bm = blockIdx.x * 128;
    const int bn = blockIdx.y * 128;
    const int t = threadIdx.x;
    const int lane = t & 63;
    const int w = t >> 6;
    const int quad = lane >> 4;
    const int l16 = lane & 15;
    const int wm = w >> 1, wn = w & 1;

    const int srow = w * 16 + (lane >> 2);
    const int skk = (lane & 3) * 8;

    f32x4 acc[4][4];
    #pragma unroll
    for (int i = 0; i < 4; i++)
        #pragma unroll
        for (int j = 0; j < 4; j++)
            #pragma unroll
            for (int r = 0; r < 4; r++) acc[i][j][r] = 0.0f;

    int ar0 = bm + srow;        if (ar0 >= M) ar0 = M - 1;
    int ar1 = bm + srow + 64;   if (ar1 >= M) ar1 = M - 1;
    const int br0 = bn + srow;
    const int br1 = bn + srow + 64;

    const int nk = K >> 5;
    for (int kt = 0; kt < nk; kt++) {
        const int k0 = kt << 5;
        __syncthreads();
        gll16(A  + (long)ar0 * K + k0 + skk, (void*)(As + w * 512));
        gll16(A  + (long)ar1 * K + k0 + skk, (void*)(As + 2048 + w * 512));
        gll16(BT + (long)br0 * K + k0 + skk, (void*)(Bs + w * 512));
        gll16(BT + (long)br1 * K + k0 + skk, (void*)(Bs + 2048 + w * 512));
        __syncthreads();
        bf16x8 af[4], bfr[4];
        #pragma unroll
        for (int i = 0; i < 4; i++) {
            af[i]  = *(const bf16x8*)&As[(wm * 64 + i * 16 + l16) * 32 + quad * 8];
            bfr[i] = *(const bf16x8*)&Bs[(wn * 64 + i * 16 + l16) * 32 + quad * 8];
        }
        #pragma unroll
        for (int i = 0; i < 4; i++)
            #pragma unroll
            for (int j = 0; j < 4; j++)
                acc[i][j] = __builtin_amdgcn_mfma_f32_16x16x32_bf16(af[i], bfr[j], acc[i][j], 0, 0, 0);
    }

    #pragma unroll
    for (int j = 0; j < 4; j++) {
        const int gc = bn + wn * 64 + j * 16 + l16;
        const float bb = bias[gc];
        #pragma unroll
        for (int i = 0; i < 4; i++) {
            const int rbase = bm + wm * 64 + i * 16 + quad * 4;
            #pragma unroll
            for (int r = 0; r < 4; r++) {
                const int gr = rbase + r;
                if (gr < M) {
                    float v = acc[i][j][r] + bb;
                    if (TANH) {
                        ((__bf16*)Cout)[(long)gr * N + gc] = f2b(ftanh(v));
                    } else {
                        ((float*)Cout)[(long)gr * N + gc] = v;
                    }
                }
            }
        }
    }
}

extern "C" void kernel_launch(void* const* d_in, const int* in_sizes, int n_in,
                              void* d_out, int out_size, void* d_ws, size_t ws_size,
                              hipStream_t stream) {
    const float* news  = (const float*)d_in[0];
    const float* ent_f = (const float*)d_in[1];
    const float* top_f = (const float*)d_in[2];
    const int* ent_row = (const int*)d_in[3];
    const int* ent_col = (const int*)d_in[4];
    const int* top_row = (const int*)d_in[5];
    const int* top_col = (const int*)d_in[6];
    const float* W1 = (const float*)d_in[7];
    const float* b1 = (const float*)d_in[8];
    const float* W2 = (const float*)d_in[9];
    const float* b2 = (const float*)d_in[10];

    char* ws = (char*)d_ws;
    // layout (bytes) — [0, 39718336) dead after aggregate2, aliased by H:
    //   [0,       400016)    offs_e int[100001]
    //   [400016,  800032)    offs_t int[100001]
    //   [800032,  801596)    bc_e   int[391]
    //   [801596,  803160)    bc_t   int[391]
    //   [803160,  804724)    cur_e  int[391]
    //   [804724,  806288)    cur_t  int[391]
    //   [806320,  7206320)   be packed int[1.6M]
    //   [7206320, 13606320)  bt packed int[1.6M]
    //   [13606320,20006320)  se int[1.6M]
    //   [20006320,26406320)  st int[1.6M]
    //   [26406336,39206336)  entb bf16 [50000*128]
    //   [39206336,39718336)  topb bf16 [2000*128]
    //   [0,        102400000) H bf16 [100000*512] (after aggregate2)
    //   [102400000,179200000) X bf16 [100000*384]
    //   [179200000,179593216) W1T bf16 [512*384]
    //   [179593216,179724288) W2T bf16 [128*512]
    int* offs_e = (int*)(ws + 0);
    int* offs_t = (int*)(ws + 400016);
    int* bc_e   = (int*)(ws + 800032);
    int* bc_t   = (int*)(ws + 801596);
    int* cur_e  = (int*)(ws + 803160);
    int* cur_t  = (int*)(ws + 804724);
    int* be     = (int*)(ws + 806320);
    int* bt     = (int*)(ws + 7206320);
    int* se     = (int*)(ws + 13606320);
    int* st     = (int*)(ws + 20006320);
    __bf16* entb = (__bf16*)(ws + 26406336);
    __bf16* topb = (__bf16*)(ws + 39206336);
    __bf16* H   = (__bf16*)(ws + 0);
    __bf16* X   = (__bf16*)(ws + 102400000);
    __bf16* W1T = (__bf16*)(ws + 179200000);
    __bf16* W2T = (__bf16*)(ws + 179593216);

    hipMemsetAsync(ws + 800032, 0, 6256, stream);   // zero bc/cur arrays
    conv_w<<<1024, 256, 0, stream>>>(W1, W2, W1T, W2T);
    conv_feats<<<6500, 256, 0, stream>>>(ent_f, top_f, entb, topb);
    hist_buckets<<<196, 256, 0, stream>>>(ent_row, top_row, bc_e, bc_t);
    scan_buckets<<<dim3(1, 2), 512, 0, stream>>>(bc_e, bc_t, cur_e, cur_t, offs_e, offs_t);
    scatter_bucket<<<782, 256, 0, stream>>>(ent_row, ent_col, top_row, top_col,
                                            cur_e, cur_t, be, bt);
    bucket_csr<<<dim3(NBKT, 2), 256, 0, stream>>>(be, bt, bc_e, bc_t,
                                                  offs_e, offs_t, se, st);
    aggregate2<<<NN / 4, 256, 0, stream>>>(news, entb, topb, offs_e, offs_t, se, st, X);
    gemm128<1><<<dim3(782, 4), 256, 0, stream>>>(X, W1T, b1, (void*)H, NN, HID, K1);
    gemm128<0><<<dim3(782, 1), 256, 0, stream>>>(H, W2T, b2, d_out, NN, OUTD, HID);
}

// Round 5
// 580.892 us; speedup vs baseline: 2.0051x; 2.0051x over previous
//
#include <hip/hip_runtime.h>
#include <hip/hip_bf16.h>

#define NN 100000
#define NE 50000
#define NT 2000
#define DD 128
#define NEDGE 1600000
#define HID 512
#define OUTD 128
#define K1 (3*DD)   // 384
#define NBKT 391              // ceil(100000/256) buckets of 256 nodes

typedef __bf16 bf16x8 __attribute__((ext_vector_type(8)));
typedef __bf16 bf16x4 __attribute__((ext_vector_type(4)));
typedef float  f32x4  __attribute__((ext_vector_type(4)));

__device__ __forceinline__ __bf16 f2b(float f) {
    __hip_bfloat16 h = __float2bfloat16(f);
    union { __hip_bfloat16 h; __bf16 b; } u; u.h = h; return u.b;
}

__device__ __forceinline__ void gll16(const void* g, void* l) {
    __builtin_amdgcn_global_load_lds((const __attribute__((address_space(1))) void*)g,
                                     (__attribute__((address_space(3))) void*)l, 16, 0, 0);
}

__device__ __forceinline__ float ftanh(float x) {
    x = fminf(fmaxf(x, -15.f), 15.f);
    float t = __expf(2.f * x);
    return (t - 1.f) / (t + 1.f);
}

// ---- convert feature tables to bf16 ----
__global__ void conv_feats(const float* __restrict__ entf, const float* __restrict__ topf,
                           __bf16* __restrict__ entb, __bf16* __restrict__ topb) {
    long i = ((long)blockIdx.x * 256 + threadIdx.x) * 4;
    const long NEL = (long)NE * DD;   // 6.4M
    if (i < NEL) {
        float4 v = *(const float4*)(entf + i);
        *(bf16x4*)(entb + i) = bf16x4{f2b(v.x), f2b(v.y), f2b(v.z), f2b(v.w)};
    } else {
        long j = i - NEL;
        float4 v = *(const float4*)(topf + j);
        *(bf16x4*)(topb + j) = bf16x4{f2b(v.x), f2b(v.y), f2b(v.z), f2b(v.w)};
    }
}

// ---- bucket histogram: LDS-local then one global atomic per (block,bucket) ----
__global__ __launch_bounds__(256) void hist_buckets(const int* __restrict__ er,
                                                    const int* __restrict__ tr,
                                                    int* __restrict__ bc_e,
                                                    int* __restrict__ bc_t) {
    __shared__ int lhe[NBKT], lht[NBKT];
    const int tid = threadIdx.x;
    for (int i = tid; i < NBKT; i += 256) { lhe[i] = 0; lht[i] = 0; }
    __syncthreads();
    const int base = blockIdx.x * 8192;
    #pragma unroll 4
    for (int k = 0; k < 32; k++) {
        int e = base + k * 256 + tid;
        if (e < NEDGE) {
            atomicAdd(&lhe[er[e] >> 8], 1);
            atomicAdd(&lht[tr[e] >> 8], 1);
        }
    }
    __syncthreads();
    for (int i = tid; i < NBKT; i += 256) {
        if (lhe[i]) atomicAdd(&bc_e[i], lhe[i]);
        if (lht[i]) atomicAdd(&bc_t[i], lht[i]);
    }
}

// ---- scan 391 bucket counts -> inclusive bc, exclusive cursors; offs[0]=0 ----
__global__ void scan_buckets(int* __restrict__ bc_e, int* __restrict__ bc_t,
                             int* __restrict__ cur_e, int* __restrict__ cur_t,
                             int* __restrict__ offs_e, int* __restrict__ offs_t) {
    int* bc  = blockIdx.y ? bc_t : bc_e;
    int* cur = blockIdx.y ? cur_t : cur_e;
    int* offs = blockIdx.y ? offs_t : offs_e;
    __shared__ int s[512];
    int i = threadIdx.x;
    s[i] = (i < NBKT) ? bc[i] : 0;
    __syncthreads();
    #pragma unroll
    for (int off = 1; off < 512; off <<= 1) {
        int v = (i >= off) ? s[i - off] : 0;
        __syncthreads();
        s[i] += v;
        __syncthreads();
    }
    if (i < NBKT) {
        bc[i] = s[i];
        cur[i] = i ? s[i - 1] : 0;
    }
    if (i == 0) offs[0] = 0;
}

// ---- partition edges into buckets: LDS hist -> per-block run reservation ->
//      LDS-cursor placement. Global atomics: one per (block, nonempty bucket).
__global__ __launch_bounds__(256) void scatter_bucket(const int* __restrict__ er,
                                                      const int* __restrict__ ec,
                                                      const int* __restrict__ tr,
                                                      const int* __restrict__ tc,
                                                      int* __restrict__ cur_e,
                                                      int* __restrict__ cur_t,
                                                      int* __restrict__ be,
                                                      int* __restrict__ bt) {
    __shared__ int lhe[NBKT], lht[NBKT];   // counts, then local cursors
    __shared__ int lbe[NBKT], lbt[NBKT];   // reserved global bases
    const int tid = threadIdx.x;
    for (int i = tid; i < NBKT; i += 256) { lhe[i] = 0; lht[i] = 0; }
    __syncthreads();
    const int base = blockIdx.x * 4096;
    #pragma unroll 4
    for (int k = 0; k < 16; k++) {
        int e = base + k * 256 + tid;
        if (e < NEDGE) {
            atomicAdd(&lhe[er[e] >> 8], 1);
            atomicAdd(&lht[tr[e] >> 8], 1);
        }
    }
    __syncthreads();
    for (int i = tid; i < NBKT; i += 256) {
        int c = lhe[i];
        lbe[i] = c ? atomicAdd(&cur_e[i], c) : 0;
        lhe[i] = 0;
        c = lht[i];
        lbt[i] = c ? atomicAdd(&cur_t[i], c) : 0;
        lht[i] = 0;
    }
    __syncthreads();
    #pragma unroll 4
    for (int k = 0; k < 16; k++) {
        int e = base + k * 256 + tid;
        if (e < NEDGE) {
            int r = er[e];
            int b = r >> 8;
            int p = lbe[b] + atomicAdd(&lhe[b], 1);
            be[p] = ((r & 255) << 16) | ec[e];
            r = tr[e];
            b = r >> 8;
            p = lbt[b] + atomicAdd(&lht[b], 1);
            bt[p] = ((r & 255) << 16) | tc[e];
        }
    }
}

// ---- per-bucket exact CSR: local hist + scan -> offs + reorder cols ----
__global__ __launch_bounds__(256) void bucket_csr(const int* __restrict__ be,
                                                  const int* __restrict__ bt,
                                                  const int* __restrict__ bc_e,
                                                  const int* __restrict__ bc_t,
                                                  int* __restrict__ offs_e,
                                                  int* __restrict__ offs_t,
                                                  int* __restrict__ se,
                                                  int* __restrict__ st) {
    const int* buf = blockIdx.y ? bt : be;
    const int* bc  = blockIdx.y ? bc_t : bc_e;
    int* offs      = blockIdx.y ? offs_t : offs_e;
    int* sout      = blockIdx.y ? st : se;
    const int b = blockIdx.x;
    const int tid = threadIdx.x;
    const int start = b ? bc[b - 1] : 0;
    const int cnt = bc[b] - start;

    __shared__ int scn[256];
    __shared__ int lcur[256];
    scn[tid] = 0;
    __syncthreads();
    for (int i = tid; i < cnt; i += 256)
        atomicAdd(&scn[buf[start + i] >> 16], 1);
    __syncthreads();
    #pragma unroll
    for (int off = 1; off < 256; off <<= 1) {
        int v = (tid >= off) ? scn[tid - off] : 0;
        __syncthreads();
        scn[tid] += v;
        __syncthreads();
    }
    const int node = b * 256 + tid;
    if (node < NN) offs[node + 1] = start + scn[tid];
    lcur[tid] = start + (tid ? scn[tid - 1] : 0);
    __syncthreads();
    for (int i = tid; i < cnt; i += 256) {
        int v = buf[start + i];
        int p = atomicAdd(&lcur[v >> 16], 1);
        sout[p] = v & 0xFFFF;
    }
}

// ---- gather-aggregate (bf16 tables) + fused X build ----
// one wave per node; quarter-wave per edge (16 lanes x bf16x8 = 16B/lane),
// 4x unroll -> up to 8 x 16B gathers in flight per wave.
__global__ __launch_bounds__(256) void aggregate2(const float* __restrict__ news,
                                                  const __bf16* __restrict__ entb,
                                                  const __bf16* __restrict__ topb,
                                                  const int* __restrict__ offs_e,
                                                  const int* __restrict__ offs_t,
                                                  const int* __restrict__ se,
                                                  const int* __restrict__ st,
                                                  __bf16* __restrict__ X) {
    const int wave = threadIdx.x >> 6, lane = threadIdx.x & 63;
    const int node = blockIdx.x * 4 + wave;
    if (node >= NN) return;
    const int h = lane >> 4;        // 0..3: edge phase
    const int d = (lane & 15) * 8;  // dim group of 8

    float ea[8] = {0,0,0,0,0,0,0,0};
    float pa[8] = {0,0,0,0,0,0,0,0};

    const int s0 = offs_e[node], s1 = offs_e[node + 1];
    int i = s0 + h;
    for (; i + 12 < s1; i += 16) {
        int c0 = se[i], c1 = se[i + 4], c2 = se[i + 8], c3 = se[i + 12];
        bf16x8 v0 = *(const bf16x8*)(entb + (long)c0 * DD + d);
        bf16x8 v1 = *(const bf16x8*)(entb + (long)c1 * DD + d);
        bf16x8 v2 = *(const bf16x8*)(entb + (long)c2 * DD + d);
        bf16x8 v3 = *(const bf16x8*)(entb + (long)c3 * DD + d);
        #pragma unroll
        for (int j = 0; j < 8; j++)
            ea[j] += ((float)v0[j] + (float)v1[j]) + ((float)v2[j] + (float)v3[j]);
    }
    for (; i < s1; i += 4) {
        bf16x8 v = *(const bf16x8*)(entb + (long)se[i] * DD + d);
        #pragma unroll
        for (int j = 0; j < 8; j++) ea[j] += (float)v[j];
    }

    const int t0 = offs_t[node], t1 = offs_t[node + 1];
    i = t0 + h;
    for (; i + 12 < t1; i += 16) {
        int c0 = st[i], c1 = st[i + 4], c2 = st[i + 8], c3 = st[i + 12];
        bf16x8 v0 = *(const bf16x8*)(topb + (long)c0 * DD + d);
        bf16x8 v1 = *(const bf16x8*)(topb + (long)c1 * DD + d);
        bf16x8 v2 = *(const bf16x8*)(topb + (long)c2 * DD + d);
        bf16x8 v3 = *(const bf16x8*)(topb + (long)c3 * DD + d);
        #pragma unroll
        for (int j = 0; j < 8; j++)
            pa[j] += ((float)v0[j] + (float)v1[j]) + ((float)v2[j] + (float)v3[j]);
    }
    for (; i < t1; i += 4) {
        bf16x8 v = *(const bf16x8*)(topb + (long)st[i] * DD + d);
        #pragma unroll
        for (int j = 0; j < 8; j++) pa[j] += (float)v[j];
    }

    // reduce the 4 edge-phases (lanes differing in bits 4,5)
    #pragma unroll
    for (int j = 0; j < 8; j++) {
        ea[j] += __shfl_xor(ea[j], 16, 64);
        ea[j] += __shfl_xor(ea[j], 32, 64);
        pa[j] += __shfl_xor(pa[j], 16, 64);
        pa[j] += __shfl_xor(pa[j], 32, 64);
    }

    const float ie = 1.0f / ((float)(s1 - s0) + 1e-8f);
    const float it = 1.0f / ((float)(t1 - t0) + 1e-8f);
    __bf16* xr = X + (long)node * K1;
    if (h == 0) {
        float4 n0 = *(const float4*)(news + (long)node * DD + d);
        float4 n1 = *(const float4*)(news + (long)node * DD + d + 4);
        *(bf16x8*)(xr + d) = bf16x8{f2b(n0.x), f2b(n0.y), f2b(n0.z), f2b(n0.w),
                                    f2b(n1.x), f2b(n1.y), f2b(n1.z), f2b(n1.w)};
    } else if (h == 1) {
        *(bf16x8*)(xr + DD + d) = bf16x8{f2b(ea[0]*ie), f2b(ea[1]*ie), f2b(ea[2]*ie), f2b(ea[3]*ie),
                                         f2b(ea[4]*ie), f2b(ea[5]*ie), f2b(ea[6]*ie), f2b(ea[7]*ie)};
    } else if (h == 2) {
        *(bf16x8*)(xr + 2*DD + d) = bf16x8{f2b(pa[0]*it), f2b(pa[1]*it), f2b(pa[2]*it), f2b(pa[3]*it),
                                           f2b(pa[4]*it), f2b(pa[5]*it), f2b(pa[6]*it), f2b(pa[7]*it)};
    }
}

// ---- W1 [384,512] -> W1T bf16 [512,384]; W2 [512,128] -> W2T bf16 [128,512] ----
__global__ void conv_w(const float* __restrict__ W1, const float* __restrict__ W2,
                       __bf16* __restrict__ W1T, __bf16* __restrict__ W2T) {
    int i = blockIdx.x * 256 + threadIdx.x;
    if (i < K1 * HID) {
        int k = i / HID, n = i % HID;
        W1T[n * K1 + k] = f2b(W1[i]);
    } else {
        int j = i - K1 * HID;
        if (j < HID * OUTD) {
            int k = j / OUTD, n = j % OUTD;
            W2T[n * HID + k] = f2b(W2[j]);
        }
    }
}

// ---- m97-style 128x128 GEMM: C[M,N] = act(A[M,K] @ BT[N,K]^T + bias) ----
template<int TANH>
__global__ __launch_bounds__(256) void gemm128(const __bf16* __restrict__ A,
                                               const __bf16* __restrict__ BT,
                                               const float* __restrict__ bias,
                                               void* __restrict__ Cout,
                                               int M, int N, int K) {
    __shared__ __bf16 As[128 * 32];
    __shared__ __bf16 Bs[128 * 32];
    const int bm = blockIdx.x * 128;
    const int bn = blockIdx.y * 128;
    const int t = threadIdx.x;
    const int lane = t & 63;
    const int w = t >> 6;
    const int quad = lane >> 4;
    const int l16 = lane & 15;
    const int wm = w >> 1, wn = w & 1;

    const int srow = w * 16 + (lane >> 2);
    const int skk = (lane & 3) * 8;

    f32x4 acc[4][4];
    #pragma unroll
    for (int i = 0; i < 4; i++)
        #pragma unroll
        for (int j = 0; j < 4; j++)
            #pragma unroll
            for (int r = 0; r < 4; r++) acc[i][j][r] = 0.0f;

    int ar0 = bm + srow;        if (ar0 >= M) ar0 = M - 1;
    int ar1 = bm + srow + 64;   if (ar1 >= M) ar1 = M - 1;
    const int br0 = bn + srow;
    const int br1 = bn + srow + 64;

    const int nk = K >> 5;
    for (int kt = 0; kt < nk; kt++) {
        const int k0 = kt << 5;
        __syncthreads();
        gll16(A  + (long)ar0 * K + k0 + skk, (void*)(As + w * 512));
        gll16(A  + (long)ar1 * K + k0 + skk, (void*)(As + 2048 + w * 512));
        gll16(BT + (long)br0 * K + k0 + skk, (void*)(Bs + w * 512));
        gll16(BT + (long)br1 * K + k0 + skk, (void*)(Bs + 2048 + w * 512));
        __syncthreads();
        bf16x8 af[4], bfr[4];
        #pragma unroll
        for (int i = 0; i < 4; i++) {
            af[i]  = *(const bf16x8*)&As[(wm * 64 + i * 16 + l16) * 32 + quad * 8];
            bfr[i] = *(const bf16x8*)&Bs[(wn * 64 + i * 16 + l16) * 32 + quad * 8];
        }
        #pragma unroll
        for (int i = 0; i < 4; i++)
            #pragma unroll
            for (int j = 0; j < 4; j++)
                acc[i][j] = __builtin_amdgcn_mfma_f32_16x16x32_bf16(af[i], bfr[j], acc[i][j], 0, 0, 0);
    }

    #pragma unroll
    for (int j = 0; j < 4; j++) {
        const int gc = bn + wn * 64 + j * 16 + l16;
        const float bb = bias[gc];
        #pragma unroll
        for (int i = 0; i < 4; i++) {
            const int rbase = bm + wm * 64 + i * 16 + quad * 4;
            #pragma unroll
            for (int r = 0; r < 4; r++) {
                const int gr = rbase + r;
                if (gr < M) {
                    float v = acc[i][j][r] + bb;
                    if (TANH) {
                        ((__bf16*)Cout)[(long)gr * N + gc] = f2b(ftanh(v));
                    } else {
                        ((float*)Cout)[(long)gr * N + gc] = v;
                    }
                }
            }
        }
    }
}

extern "C" void kernel_launch(void* const* d_in, const int* in_sizes, int n_in,
                              void* d_out, int out_size, void* d_ws, size_t ws_size,
                              hipStream_t stream) {
    const float* news  = (const float*)d_in[0];
    const float* ent_f = (const float*)d_in[1];
    const float* top_f = (const float*)d_in[2];
    const int* ent_row = (const int*)d_in[3];
    const int* ent_col = (const int*)d_in[4];
    const int* top_row = (const int*)d_in[5];
    const int* top_col = (const int*)d_in[6];
    const float* W1 = (const float*)d_in[7];
    const float* b1 = (const float*)d_in[8];
    const float* W2 = (const float*)d_in[9];
    const float* b2 = (const float*)d_in[10];

    char* ws = (char*)d_ws;
    // layout (bytes) — [0, 39718336) dead after aggregate2, aliased by H:
    //   [0,       400016)    offs_e int[100001]
    //   [400016,  800032)    offs_t int[100001]
    //   [800032,  801596)    bc_e   int[391]
    //   [801596,  803160)    bc_t   int[391]
    //   [803160,  804724)    cur_e  int[391]
    //   [804724,  806288)    cur_t  int[391]
    //   [806320,  7206320)   be packed int[1.6M]
    //   [7206320, 13606320)  bt packed int[1.6M]
    //   [13606320,20006320)  se int[1.6M]
    //   [20006320,26406320)  st int[1.6M]
    //   [26406336,39206336)  entb bf16 [50000*128]
    //   [39206336,39718336)  topb bf16 [2000*128]
    //   [0,        102400000) H bf16 [100000*512] (after aggregate2)
    //   [102400000,179200000) X bf16 [100000*384]
    //   [179200000,179593216) W1T bf16 [512*384]
    //   [179593216,179724288) W2T bf16 [128*512]
    int* offs_e = (int*)(ws + 0);
    int* offs_t = (int*)(ws + 400016);
    int* bc_e   = (int*)(ws + 800032);
    int* bc_t   = (int*)(ws + 801596);
    int* cur_e  = (int*)(ws + 803160);
    int* cur_t  = (int*)(ws + 804724);
    int* be     = (int*)(ws + 806320);
    int* bt     = (int*)(ws + 7206320);
    int* se     = (int*)(ws + 13606320);
    int* st     = (int*)(ws + 20006320);
    __bf16* entb = (__bf16*)(ws + 26406336);
    __bf16* topb = (__bf16*)(ws + 39206336);
    __bf16* H   = (__bf16*)(ws + 0);
    __bf16* X   = (__bf16*)(ws + 102400000);
    __bf16* W1T = (__bf16*)(ws + 179200000);
    __bf16* W2T = (__bf16*)(ws + 179593216);

    hipMemsetAsync(ws + 800032, 0, 6256, stream);   // zero bc/cur arrays
    conv_w<<<1024, 256, 0, stream>>>(W1, W2, W1T, W2T);
    conv_feats<<<6500, 256, 0, stream>>>(ent_f, top_f, entb, topb);
    hist_buckets<<<196, 256, 0, stream>>>(ent_row, top_row, bc_e, bc_t);
    scan_buckets<<<dim3(1, 2), 512, 0, stream>>>(bc_e, bc_t, cur_e, cur_t, offs_e, offs_t);
    scatter_bucket<<<392, 256, 0, stream>>>(ent_row, ent_col, top_row, top_col,
                                            cur_e, cur_t, be, bt);
    bucket_csr<<<dim3(NBKT, 2), 256, 0, stream>>>(be, bt, bc_e, bc_t,
                                                  offs_e, offs_t, se, st);
    aggregate2<<<NN / 4, 256, 0, stream>>>(news, entb, topb, offs_e, offs_t, se, st, X);
    gemm128<1><<<dim3(782, 4), 256, 0, stream>>>(X, W1T, b1, (void*)H, NN, HID, K1);
    gemm128<0><<<dim3(782, 1), 256, 0, stream>>>(H, W2T, b2, d_out, NN, OUTD, HID);
}

// Round 6
// 530.641 us; speedup vs baseline: 2.1949x; 1.0947x over previous
//
#include <hip/hip_runtime.h>
#include <hip/hip_bf16.h>

#define NN 100000
#define NE 50000
#define NT 2000
#define DD 128
#define NEDGE 1600000
#define HID 512
#define OUTD 128
#define K1 (3*DD)   // 384
#define NBKT 391              // ceil(100000/256) buckets of 256 nodes

typedef __bf16 bf16x8 __attribute__((ext_vector_type(8)));
typedef __bf16 bf16x4 __attribute__((ext_vector_type(4)));
typedef float  f32x4  __attribute__((ext_vector_type(4)));

__device__ __forceinline__ __bf16 f2b(float f) {
    __hip_bfloat16 h = __float2bfloat16(f);
    union { __hip_bfloat16 h; __bf16 b; } u; u.h = h; return u.b;
}

__device__ __forceinline__ void gll16(const void* g, void* l) {
    __builtin_amdgcn_global_load_lds((const __attribute__((address_space(1))) void*)g,
                                     (__attribute__((address_space(3))) void*)l, 16, 0, 0);
}

__device__ __forceinline__ float ftanh(float x) {
    x = fminf(fmaxf(x, -15.f), 15.f);
    float t = __expf(2.f * x);
    return (t - 1.f) / (t + 1.f);
}

// ---- convert feature tables to bf16 ----
__global__ void conv_feats(const float* __restrict__ entf, const float* __restrict__ topf,
                           __bf16* __restrict__ entb, __bf16* __restrict__ topb) {
    long i = ((long)blockIdx.x * 256 + threadIdx.x) * 4;
    const long NEL = (long)NE * DD;   // 6.4M
    if (i < NEL) {
        float4 v = *(const float4*)(entf + i);
        *(bf16x4*)(entb + i) = bf16x4{f2b(v.x), f2b(v.y), f2b(v.z), f2b(v.w)};
    } else {
        long j = i - NEL;
        float4 v = *(const float4*)(topf + j);
        *(bf16x4*)(topb + j) = bf16x4{f2b(v.x), f2b(v.y), f2b(v.z), f2b(v.w)};
    }
}

// ---- bucket histogram: LDS-local then one global atomic per (block,bucket) ----
__global__ __launch_bounds__(256) void hist_buckets(const int* __restrict__ er,
                                                    const int* __restrict__ tr,
                                                    int* __restrict__ bc_e,
                                                    int* __restrict__ bc_t) {
    __shared__ int lhe[NBKT], lht[NBKT];
    const int tid = threadIdx.x;
    for (int i = tid; i < NBKT; i += 256) { lhe[i] = 0; lht[i] = 0; }
    __syncthreads();
    const int base = blockIdx.x * 8192;
    #pragma unroll 4
    for (int k = 0; k < 32; k++) {
        int e = base + k * 256 + tid;
        if (e < NEDGE) {
            atomicAdd(&lhe[er[e] >> 8], 1);
            atomicAdd(&lht[tr[e] >> 8], 1);
        }
    }
    __syncthreads();
    for (int i = tid; i < NBKT; i += 256) {
        if (lhe[i]) atomicAdd(&bc_e[i], lhe[i]);
        if (lht[i]) atomicAdd(&bc_t[i], lht[i]);
    }
}

// ---- scan 391 bucket counts -> inclusive bc, exclusive cursors; offs[0]=0 ----
__global__ void scan_buckets(int* __restrict__ bc_e, int* __restrict__ bc_t,
                             int* __restrict__ cur_e, int* __restrict__ cur_t,
                             int* __restrict__ offs_e, int* __restrict__ offs_t) {
    int* bc  = blockIdx.y ? bc_t : bc_e;
    int* cur = blockIdx.y ? cur_t : cur_e;
    int* offs = blockIdx.y ? offs_t : offs_e;
    __shared__ int s[512];
    int i = threadIdx.x;
    s[i] = (i < NBKT) ? bc[i] : 0;
    __syncthreads();
    #pragma unroll
    for (int off = 1; off < 512; off <<= 1) {
        int v = (i >= off) ? s[i - off] : 0;
        __syncthreads();
        s[i] += v;
        __syncthreads();
    }
    if (i < NBKT) {
        bc[i] = s[i];
        cur[i] = i ? s[i - 1] : 0;
    }
    if (i == 0) offs[0] = 0;
}

// ---- partition edges into buckets: LDS hist -> per-block run reservation ->
//      LDS-cursor placement. Global atomics: one per (block, nonempty bucket).
__global__ __launch_bounds__(256) void scatter_bucket(const int* __restrict__ er,
                                                      const int* __restrict__ ec,
                                                      const int* __restrict__ tr,
                                                      const int* __restrict__ tc,
                                                      int* __restrict__ cur_e,
                                                      int* __restrict__ cur_t,
                                                      int* __restrict__ be,
                                                      int* __restrict__ bt) {
    __shared__ int lhe[NBKT], lht[NBKT];   // counts, then local cursors
    __shared__ int lbe[NBKT], lbt[NBKT];   // reserved global bases
    const int tid = threadIdx.x;
    for (int i = tid; i < NBKT; i += 256) { lhe[i] = 0; lht[i] = 0; }
    __syncthreads();
    const int base = blockIdx.x * 4096;
    #pragma unroll 4
    for (int k = 0; k < 16; k++) {
        int e = base + k * 256 + tid;
        if (e < NEDGE) {
            atomicAdd(&lhe[er[e] >> 8], 1);
            atomicAdd(&lht[tr[e] >> 8], 1);
        }
    }
    __syncthreads();
    for (int i = tid; i < NBKT; i += 256) {
        int c = lhe[i];
        lbe[i] = c ? atomicAdd(&cur_e[i], c) : 0;
        lhe[i] = 0;
        c = lht[i];
        lbt[i] = c ? atomicAdd(&cur_t[i], c) : 0;
        lht[i] = 0;
    }
    __syncthreads();
    #pragma unroll 4
    for (int k = 0; k < 16; k++) {
        int e = base + k * 256 + tid;
        if (e < NEDGE) {
            int r = er[e];
            int b = r >> 8;
            int p = lbe[b] + atomicAdd(&lhe[b], 1);
            be[p] = ((r & 255) << 16) | ec[e];
            r = tr[e];
            b = r >> 8;
            p = lbt[b] + atomicAdd(&lht[b], 1);
            bt[p] = ((r & 255) << 16) | tc[e];
        }
    }
}

// ---- per-bucket exact CSR: local hist + scan -> offs + reorder cols ----
__global__ __launch_bounds__(256) void bucket_csr(const int* __restrict__ be,
                                                  const int* __restrict__ bt,
                                                  const int* __restrict__ bc_e,
                                                  const int* __restrict__ bc_t,
                                                  int* __restrict__ offs_e,
                                                  int* __restrict__ offs_t,
                                                  int* __restrict__ se,
                                                  int* __restrict__ st) {
    const int* buf = blockIdx.y ? bt : be;
    const int* bc  = blockIdx.y ? bc_t : bc_e;
    int* offs      = blockIdx.y ? offs_t : offs_e;
    int* sout      = blockIdx.y ? st : se;
    const int b = blockIdx.x;
    const int tid = threadIdx.x;
    const int start = b ? bc[b - 1] : 0;
    const int cnt = bc[b] - start;

    __shared__ int scn[256];
    __shared__ int lcur[256];
    scn[tid] = 0;
    __syncthreads();
    for (int i = tid; i < cnt; i += 256)
        atomicAdd(&scn[buf[start + i] >> 16], 1);
    __syncthreads();
    #pragma unroll
    for (int off = 1; off < 256; off <<= 1) {
        int v = (tid >= off) ? scn[tid - off] : 0;
        __syncthreads();
        scn[tid] += v;
        __syncthreads();
    }
    const int node = b * 256 + tid;
    if (node < NN) offs[node + 1] = start + scn[tid];
    lcur[tid] = start + (tid ? scn[tid - 1] : 0);
    __syncthreads();
    for (int i = tid; i < cnt; i += 256) {
        int v = buf[start + i];
        int p = atomicAdd(&lcur[v >> 16], 1);
        sout[p] = v & 0xFFFF;
    }
}

// ---- gather-aggregate (bf16 tables) + fused X build ----
__global__ __launch_bounds__(256) void aggregate2(const float* __restrict__ news,
                                                  const __bf16* __restrict__ entb,
                                                  const __bf16* __restrict__ topb,
                                                  const int* __restrict__ offs_e,
                                                  const int* __restrict__ offs_t,
                                                  const int* __restrict__ se,
                                                  const int* __restrict__ st,
                                                  __bf16* __restrict__ X) {
    const int wave = threadIdx.x >> 6, lane = threadIdx.x & 63;
    const int node = blockIdx.x * 4 + wave;
    if (node >= NN) return;
    const int h = lane >> 4;        // 0..3: edge phase
    const int d = (lane & 15) * 8;  // dim group of 8

    float ea[8] = {0,0,0,0,0,0,0,0};
    float pa[8] = {0,0,0,0,0,0,0,0};

    const int s0 = offs_e[node], s1 = offs_e[node + 1];
    int i = s0 + h;
    for (; i + 12 < s1; i += 16) {
        int c0 = se[i], c1 = se[i + 4], c2 = se[i + 8], c3 = se[i + 12];
        bf16x8 v0 = *(const bf16x8*)(entb + (long)c0 * DD + d);
        bf16x8 v1 = *(const bf16x8*)(entb + (long)c1 * DD + d);
        bf16x8 v2 = *(const bf16x8*)(entb + (long)c2 * DD + d);
        bf16x8 v3 = *(const bf16x8*)(entb + (long)c3 * DD + d);
        #pragma unroll
        for (int j = 0; j < 8; j++)
            ea[j] += ((float)v0[j] + (float)v1[j]) + ((float)v2[j] + (float)v3[j]);
    }
    for (; i < s1; i += 4) {
        bf16x8 v = *(const bf16x8*)(entb + (long)se[i] * DD + d);
        #pragma unroll
        for (int j = 0; j < 8; j++) ea[j] += (float)v[j];
    }

    const int t0 = offs_t[node], t1 = offs_t[node + 1];
    i = t0 + h;
    for (; i + 12 < t1; i += 16) {
        int c0 = st[i], c1 = st[i + 4], c2 = st[i + 8], c3 = st[i + 12];
        bf16x8 v0 = *(const bf16x8*)(topb + (long)c0 * DD + d);
        bf16x8 v1 = *(const bf16x8*)(topb + (long)c1 * DD + d);
        bf16x8 v2 = *(const bf16x8*)(topb + (long)c2 * DD + d);
        bf16x8 v3 = *(const bf16x8*)(topb + (long)c3 * DD + d);
        #pragma unroll
        for (int j = 0; j < 8; j++)
            pa[j] += ((float)v0[j] + (float)v1[j]) + ((float)v2[j] + (float)v3[j]);
    }
    for (; i < t1; i += 4) {
        bf16x8 v = *(const bf16x8*)(topb + (long)st[i] * DD + d);
        #pragma unroll
        for (int j = 0; j < 8; j++) pa[j] += (float)v[j];
    }

    #pragma unroll
    for (int j = 0; j < 8; j++) {
        ea[j] += __shfl_xor(ea[j], 16, 64);
        ea[j] += __shfl_xor(ea[j], 32, 64);
        pa[j] += __shfl_xor(pa[j], 16, 64);
        pa[j] += __shfl_xor(pa[j], 32, 64);
    }

    const float ie = 1.0f / ((float)(s1 - s0) + 1e-8f);
    const float it = 1.0f / ((float)(t1 - t0) + 1e-8f);
    __bf16* xr = X + (long)node * K1;
    if (h == 0) {
        float4 n0 = *(const float4*)(news + (long)node * DD + d);
        float4 n1 = *(const float4*)(news + (long)node * DD + d + 4);
        *(bf16x8*)(xr + d) = bf16x8{f2b(n0.x), f2b(n0.y), f2b(n0.z), f2b(n0.w),
                                    f2b(n1.x), f2b(n1.y), f2b(n1.z), f2b(n1.w)};
    } else if (h == 1) {
        *(bf16x8*)(xr + DD + d) = bf16x8{f2b(ea[0]*ie), f2b(ea[1]*ie), f2b(ea[2]*ie), f2b(ea[3]*ie),
                                         f2b(ea[4]*ie), f2b(ea[5]*ie), f2b(ea[6]*ie), f2b(ea[7]*ie)};
    } else if (h == 2) {
        *(bf16x8*)(xr + 2*DD + d) = bf16x8{f2b(pa[0]*it), f2b(pa[1]*it), f2b(pa[2]*it), f2b(pa[3]*it),
                                           f2b(pa[4]*it), f2b(pa[5]*it), f2b(pa[6]*it), f2b(pa[7]*it)};
    }
}

// ---- W1 [384,512] -> W1T bf16 [512,384]; W2 [512,128] -> W2T bf16 [128,512] ----
__global__ void conv_w(const float* __restrict__ W1, const float* __restrict__ W2,
                       __bf16* __restrict__ W1T, __bf16* __restrict__ W2T) {
    int i = blockIdx.x * 256 + threadIdx.x;
    if (i < K1 * HID) {
        int k = i / HID, n = i % HID;
        W1T[n * K1 + k] = f2b(W1[i]);
    } else {
        int j = i - K1 * HID;
        if (j < HID * OUTD) {
            int k = j / OUTD, n = j % OUTD;
            W2T[n * HID + k] = f2b(W2[j]);
        }
    }
}

// ======== fused MLP: out = (tanh(X@W1T^T + b1)) @ W2T^T + b2 ========
// 128-row tile per block; loop over 4 HID-chunks: H-chunk via MFMA -> tanh ->
// LDS (swizzled) -> accumulate O. XOR swizzle keeps global_load_lds coalesced
// AND fragment ds_read_b128 at 2-way bank aliasing (free).

// stage a [128 x 32] bf16 tile (swizzled) from row-major src
__device__ __forceinline__ void stage_tile(const __bf16* __restrict__ src, int ldK,
                                           int k0, int row0, int rowmax,
                                           __bf16* lds, int w, int lane) {
    #pragma unroll
    for (int half = 0; half < 2; half++) {
        int ss = w * 64 + half * 256 + lane;
        int r = ss >> 2;
        int sw = (r & 3) ^ ((r >> 2) & 3);
        int c = (ss & 3) ^ sw;
        int gr = row0 + r; if (gr >= rowmax) gr = rowmax - 1;
        gll16(src + (long)gr * ldK + k0 + c * 8,
              lds + (w * 64 + half * 256) * 8);
    }
}

// read fragment (logical row r, k-chunk q) from swizzled [128 x 32] tile
__device__ __forceinline__ bf16x8 frag(const __bf16* lds, int r, int q) {
    int sw = (r & 3) ^ ((r >> 2) & 3);
    return *(const bf16x8*)(lds + (r * 4 + (q ^ sw)) * 8);
}

// Hs [128 rows x 128 k] swizzled: chunk16 = kk*4+quad
__device__ __forceinline__ void hs_write(__bf16* Hs, int r, int c, __bf16 v) {
    int ch = c >> 3;
    int pch = ((((ch >> 2) ^ ((r >> 2) & 3)) << 2) | ((ch & 3) ^ (r & 3)));
    Hs[(r * 16 + pch) * 8 + (c & 7)] = v;
}
__device__ __forceinline__ bf16x8 hs_frag(const __bf16* Hs, int r, int kk, int q) {
    int pch = (((kk ^ ((r >> 2) & 3)) << 2) | (q ^ (r & 3)));
    return *(const bf16x8*)(Hs + (r * 16 + pch) * 8);
}

__global__ __launch_bounds__(256, 2) void mlp_fused(const __bf16* __restrict__ X,
                                                    const __bf16* __restrict__ W1T,
                                                    const float* __restrict__ b1,
                                                    const __bf16* __restrict__ W2T,
                                                    const float* __restrict__ b2,
                                                    float* __restrict__ out) {
    __shared__ __bf16 Xs[128 * 32];    // 8 KB
    __shared__ __bf16 Ws[128 * 32];    // 8 KB (W1 rows, then W2 rows)
    __shared__ __bf16 Hs[128 * 128];   // 32 KB
    const int bm = blockIdx.x * 128;
    const int t = threadIdx.x;
    const int lane = t & 63;
    const int w = t >> 6;
    const int quad = lane >> 4;
    const int l16 = lane & 15;
    const int wm = w >> 1, wn = w & 1;

    f32x4 oacc[4][4];
    #pragma unroll
    for (int i = 0; i < 4; i++)
        #pragma unroll
        for (int j = 0; j < 4; j++)
            #pragma unroll
            for (int r = 0; r < 4; r++) oacc[i][j][r] = 0.0f;

    for (int nc = 0; nc < 4; nc++) {
        // ---- H-chunk: H[128 x 128] = X_tile @ W1T[nc*128..+128]^T ----
        f32x4 hacc[4][4];
        #pragma unroll
        for (int i = 0; i < 4; i++)
            #pragma unroll
            for (int j = 0; j < 4; j++)
                #pragma unroll
                for (int r = 0; r < 4; r++) hacc[i][j][r] = 0.0f;

        for (int kt = 0; kt < K1 / 32; kt++) {
            __syncthreads();
            stage_tile(X,   K1, kt * 32, bm,       NN,  Xs, w, lane);
            stage_tile(W1T, K1, kt * 32, nc * 128, HID, Ws, w, lane);
            __syncthreads();
            bf16x8 af[4], bfr[4];
            #pragma unroll
            for (int i = 0; i < 4; i++) {
                af[i]  = frag(Xs, wm * 64 + i * 16 + l16, quad);
                bfr[i] = frag(Ws, wn * 64 + i * 16 + l16, quad);
            }
            #pragma unroll
            for (int i = 0; i < 4; i++)
                #pragma unroll
                for (int j = 0; j < 4; j++)
                    hacc[i][j] = __builtin_amdgcn_mfma_f32_16x16x32_bf16(af[i], bfr[j], hacc[i][j], 0, 0, 0);
        }

        // bias + tanh -> Hs (C/D layout: row=quad*4+reg, col=l16)
        #pragma unroll
        for (int j = 0; j < 4; j++) {
            const int col = wn * 64 + j * 16 + l16;
            const float bb = b1[nc * 128 + col];
            #pragma unroll
            for (int i = 0; i < 4; i++) {
                const int rbase = wm * 64 + i * 16 + quad * 4;
                #pragma unroll
                for (int r = 0; r < 4; r++)
                    hs_write(Hs, rbase + r, col, f2b(ftanh(hacc[i][j][r] + bb)));
            }
        }

        // ---- O += H_chunk @ W2T[:, nc*128..+128]^T ----
        for (int kk = 0; kk < 4; kk++) {
            __syncthreads();
            stage_tile(W2T, HID, nc * 128 + kk * 32, 0, OUTD, Ws, w, lane);
            __syncthreads();
            bf16x8 af[4], bfr[4];
            #pragma unroll
            for (int i = 0; i < 4; i++) {
                af[i]  = hs_frag(Hs, wm * 64 + i * 16 + l16, kk, quad);
                bfr[i] = frag(Ws, wn * 64 + i * 16 + l16, quad);
            }
            #pragma unroll
            for (int i = 0; i < 4; i++)
                #pragma unroll
                for (int j = 0; j < 4; j++)
                    oacc[i][j] = __builtin_amdgcn_mfma_f32_16x16x32_bf16(af[i], bfr[j], oacc[i][j], 0, 0, 0);
        }
    }

    // epilogue: out f32 [NN x 128]
    #pragma unroll
    for (int j = 0; j < 4; j++) {
        const int gc = wn * 64 + j * 16 + l16;
        const float bb = b2[gc];
        #pragma unroll
        for (int i = 0; i < 4; i++) {
            const int rbase = bm + wm * 64 + i * 16 + quad * 4;
            #pragma unroll
            for (int r = 0; r < 4; r++) {
                const int gr = rbase + r;
                if (gr < NN) out[(long)gr * OUTD + gc] = oacc[i][j][r] + bb;
            }
        }
    }
}

extern "C" void kernel_launch(void* const* d_in, const int* in_sizes, int n_in,
                              void* d_out, int out_size, void* d_ws, size_t ws_size,
                              hipStream_t stream) {
    const float* news  = (const float*)d_in[0];
    const float* ent_f = (const float*)d_in[1];
    const float* top_f = (const float*)d_in[2];
    const int* ent_row = (const int*)d_in[3];
    const int* ent_col = (const int*)d_in[4];
    const int* top_row = (const int*)d_in[5];
    const int* top_col = (const int*)d_in[6];
    const float* W1 = (const float*)d_in[7];
    const float* b1 = (const float*)d_in[8];
    const float* W2 = (const float*)d_in[9];
    const float* b2 = (const float*)d_in[10];

    char* ws = (char*)d_ws;
    //   [0,       400016)    offs_e int[100001]
    //   [400016,  800032)    offs_t int[100001]
    //   [800032,  801596)    bc_e   int[391]
    //   [801596,  803160)    bc_t   int[391]
    //   [803160,  804724)    cur_e  int[391]
    //   [804724,  806288)    cur_t  int[391]
    //   [806320,  7206320)   be packed int[1.6M]
    //   [7206320, 13606320)  bt packed int[1.6M]
    //   [13606320,20006320)  se int[1.6M]
    //   [20006320,26406320)  st int[1.6M]
    //   [26406336,39206336)  entb bf16 [50000*128]
    //   [39206336,39718336)  topb bf16 [2000*128]
    //   [102400000,179200000) X bf16 [100000*384]
    //   [179200000,179593216) W1T bf16 [512*384]
    //   [179593216,179724288) W2T bf16 [128*512]
    int* offs_e = (int*)(ws + 0);
    int* offs_t = (int*)(ws + 400016);
    int* bc_e   = (int*)(ws + 800032);
    int* bc_t   = (int*)(ws + 801596);
    int* cur_e  = (int*)(ws + 803160);
    int* cur_t  = (int*)(ws + 804724);
    int* be     = (int*)(ws + 806320);
    int* bt     = (int*)(ws + 7206320);
    int* se     = (int*)(ws + 13606320);
    int* st     = (int*)(ws + 20006320);
    __bf16* entb = (__bf16*)(ws + 26406336);
    __bf16* topb = (__bf16*)(ws + 39206336);
    __bf16* X   = (__bf16*)(ws + 102400000);
    __bf16* W1T = (__bf16*)(ws + 179200000);
    __bf16* W2T = (__bf16*)(ws + 179593216);

    hipMemsetAsync(ws + 800032, 0, 6256, stream);   // zero bc/cur arrays
    conv_w<<<1024, 256, 0, stream>>>(W1, W2, W1T, W2T);
    conv_feats<<<6500, 256, 0, stream>>>(ent_f, top_f, entb, topb);
    hist_buckets<<<196, 256, 0, stream>>>(ent_row, top_row, bc_e, bc_t);
    scan_buckets<<<dim3(1, 2), 512, 0, stream>>>(bc_e, bc_t, cur_e, cur_t, offs_e, offs_t);
    scatter_bucket<<<392, 256, 0, stream>>>(ent_row, ent_col, top_row, top_col,
                                            cur_e, cur_t, be, bt);
    bucket_csr<<<dim3(NBKT, 2), 256, 0, stream>>>(be, bt, bc_e, bc_t,
                                                  offs_e, offs_t, se, st);
    aggregate2<<<NN / 4, 256, 0, stream>>>(news, entb, topb, offs_e, offs_t, se, st, X);
    mlp_fused<<<782, 256, 0, stream>>>(X, W1T, b1, W2T, b2, (float*)d_out);
}